// Round 2
// baseline (165.495 us; speedup 1.0000x reference)
//
#include <hip/hip_runtime.h>

// LayerHypercube: out[b, f*1024+o] = sum_j x[b, o^(1<<j)] * w[f,j,o] + bias[f,o] + x[b,o]
// B=2048, F=16, O=I=1024, BITS=10. fm is analytic (o ^ (1<<j)) -- not read.
//
// R1 analysis: 159 us = ~750 cyc/wave-iteration = one fully exposed
// load->shuffle->fma chain. Fix: software-pipeline over b (prefetch rows
// bi+2,bi+3 while computing bi,bi+1), 2-row ILP, 2048 blocks (8/CU sched),
// nontemporal stores for the streamed 134 MB output.
//
// Mapping: wave owns one 64-wide o-chunk (lane <-> o) and 4 feature maps
// (44 weight regs/lane, loaded once). j<6 gather = __shfl_xor; j=6..9 =
// coalesced load of lane l from chunk c^{1,2,4,8} (L1/L2-hit).

#define BTILE 16

__global__ __launch_bounds__(256, 4) void hypercube_kernel(
    const float* __restrict__ x,      // [2048][1024]
    const float* __restrict__ w,      // [16][10][1024]
    const float* __restrict__ bias,   // [16][1024]
    float* __restrict__ out)          // [2048][16*1024]
{
    const int lane  = threadIdx.x & 63;
    const int wave  = threadIdx.x >> 6;
    const int chunk = blockIdx.x & 15;   // which 64-wide o-chunk
    const int btile = blockIdx.x >> 4;   // which batch tile
    const int b0    = btile * BTILE;
    const int f0    = wave * 4;          // this wave's 4 feature maps
    const int obase = chunk * 64;
    const int o     = obase + lane;

    // Weights for 4 f's, this lane's o: 40 + 4 regs, loaded once per block.
    float wr[4][10], br[4];
    #pragma unroll
    for (int ff = 0; ff < 4; ++ff) {
        const int f = f0 + ff;
        #pragma unroll
        for (int j = 0; j < 10; ++j)
            wr[ff][j] = w[(f * 10 + j) * 1024 + o];
        br[ff] = bias[f * 1024 + o];
    }

    // Partner-chunk addresses for the high XOR bits (j=6..9).
    const int a64  = (chunk ^ 1) * 64 + lane;
    const int a128 = (chunk ^ 2) * 64 + lane;
    const int a256 = (chunk ^ 4) * 64 + lane;
    const int a512 = (chunk ^ 8) * 64 + lane;

    const float* __restrict__ xb = x + (size_t)b0 * 1024;

    // Pipeline registers: current pair of rows + next pair in flight.
    float cx0[2], cx64[2], cx128[2], cx256[2], cx512[2];
    #pragma unroll
    for (int r = 0; r < 2; ++r) {
        const float* __restrict__ xr = xb + r * 1024;
        cx0[r]   = xr[o];
        cx64[r]  = xr[a64];
        cx128[r] = xr[a128];
        cx256[r] = xr[a256];
        cx512[r] = xr[a512];
    }

    #pragma unroll 1
    for (int bi = 0; bi < BTILE; bi += 2) {
        // Prefetch rows bi+2, bi+3 (clamped: last iter re-reads row 0, discarded).
        const int pb = (bi + 2 < BTILE) ? (bi + 2) : 0;
        float nx0[2], nx64[2], nx128[2], nx256[2], nx512[2];
        #pragma unroll
        for (int r = 0; r < 2; ++r) {
            const float* __restrict__ xr = xb + (size_t)(pb + r) * 1024;
            nx0[r]   = xr[o];
            nx64[r]  = xr[a64];
            nx128[r] = xr[a128];
            nx256[r] = xr[a256];
            nx512[r] = xr[a512];
        }

        // Compute the two current rows while the prefetch is in flight.
        #pragma unroll
        for (int r = 0; r < 2; ++r) {
            const int b = b0 + bi + r;
            const float s0 = __shfl_xor(cx0[r], 1);
            const float s1 = __shfl_xor(cx0[r], 2);
            const float s2 = __shfl_xor(cx0[r], 4);
            const float s3 = __shfl_xor(cx0[r], 8);
            const float s4 = __shfl_xor(cx0[r], 16);
            const float s5 = __shfl_xor(cx0[r], 32);

            float* __restrict__ ob = out + (size_t)b * (16 * 1024) + obase + lane;
            #pragma unroll
            for (int ff = 0; ff < 4; ++ff) {
                float acc = br[ff] + cx0[r];          // bias + tiled-x term
                acc = fmaf(s0,       wr[ff][0], acc);
                acc = fmaf(s1,       wr[ff][1], acc);
                acc = fmaf(s2,       wr[ff][2], acc);
                acc = fmaf(s3,       wr[ff][3], acc);
                acc = fmaf(s4,       wr[ff][4], acc);
                acc = fmaf(s5,       wr[ff][5], acc);
                acc = fmaf(cx64[r],  wr[ff][6], acc);
                acc = fmaf(cx128[r], wr[ff][7], acc);
                acc = fmaf(cx256[r], wr[ff][8], acc);
                acc = fmaf(cx512[r], wr[ff][9], acc);
                // Streaming 134 MB output, never re-read: bypass L2.
                __builtin_nontemporal_store(acc, &ob[(size_t)(f0 + ff) * 1024]);
            }
        }

        // Rotate pipeline.
        #pragma unroll
        for (int r = 0; r < 2; ++r) {
            cx0[r]   = nx0[r];
            cx64[r]  = nx64[r];
            cx128[r] = nx128[r];
            cx256[r] = nx256[r];
            cx512[r] = nx512[r];
        }
    }
}

extern "C" void kernel_launch(void* const* d_in, const int* in_sizes, int n_in,
                              void* d_out, int out_size, void* d_ws, size_t ws_size,
                              hipStream_t stream) {
    const float* x    = (const float*)d_in[0];
    const float* w    = (const float*)d_in[1];
    const float* bias = (const float*)d_in[2];
    // d_in[3] = fm (int32) -- analytic, unused.
    float* out = (float*)d_out;

    dim3 grid(16 * (2048 / BTILE));   // 2048 blocks = 8/CU scheduled
    dim3 block(256);
    hypercube_kernel<<<grid, block, 0, stream>>>(x, w, bias, out);
}

// Round 3
// 149.859 us; speedup vs baseline: 1.1043x; 1.1043x over previous
//
#include <hip/hip_runtime.h>

// LayerHypercube: out[b, f*1024+o] = sum_j x[b, o^(1<<j)] * w[f,j,o] + bias[f,o] + x[b,o]
// B=2048, F=16, O=I=1024, BITS=10. fm analytic (o^(1<<j)) -- not read.
//
// R2 post-mortem: per-row global gathers leave ~750 exposed cycles/row that
// neither TLP (R1->R2 2x waves: no change) nor manual pipelining fixed.
// R3 structure: burst-stage ALL x data a block needs into LDS up front
// (10 dwordx4/thread, deep MLP), one barrier, then a pure LDS+FMA+store loop
// with zero global loads. 8 feature maps per wave (88 weight regs) halves
// per-output DS and address overhead vs R1's 4.
//
// Per block (chunk c, BTILE=16 rows, 2 waves x 8f): LDS holds [row][slot][64]
// slots = chunks {c, c^1, c^2, c^4, c^8} (20 KB). Gather j=0..5 = LDS read at
// lane^(1<<j) (bank-permutation, conflict-free); j=6..9 = slot 1..4 at lane.
// Stores: 256 B contiguous per wave instruction, 8 per row.

#define BTILE 16
#define NSLOT 5

__global__ __launch_bounds__(128, 2) void hypercube_kernel(
    const float* __restrict__ x,      // [2048][1024]
    const float* __restrict__ w,      // [16][10][1024]
    const float* __restrict__ bias,   // [16][1024]
    float* __restrict__ out)          // [2048][16*1024]
{
    __shared__ float xs[BTILE * NSLOT * 64];   // 20 KB: [row][slot][lane]

    const int tid   = threadIdx.x;
    const int lane  = tid & 63;
    const int wave  = tid >> 6;          // 0..1
    const int chunk = blockIdx.x & 15;
    const int btile = blockIdx.x >> 4;
    const int b0    = btile * BTILE;
    const int f0    = wave * 8;
    const int o     = chunk * 64 + lane;

    // ---- Burst-stage BTILE rows x 5 chunks (1280 float4, 10 per thread) ----
    // slot s holds chunk ^ {0,1,2,4,8} = chunk ^ ((1<<s)>>1).
    #pragma unroll
    for (int it = 0; it < (BTILE * NSLOT * 64 / 4) / 128; ++it) {
        const int q    = it * 128 + tid;        // float4 index
        const int row  = q / (NSLOT * 16);      // 80 float4 per row
        const int rem  = q - row * (NSLOT * 16);
        const int slot = rem >> 4;              // 16 float4 per slot
        const int l4   = (rem & 15) << 2;
        const int src_chunk = chunk ^ ((1 << slot) >> 1);
        const float4 v = *(const float4*)&x[(size_t)(b0 + row) * 1024 + src_chunk * 64 + l4];
        *(float4*)&xs[q * 4] = v;
    }

    // ---- Weights for 8 f's at this lane's o (independent of staging) ----
    float wr[8][10], br[8];
    #pragma unroll
    for (int ff = 0; ff < 8; ++ff) {
        const int f = f0 + ff;
        #pragma unroll
        for (int j = 0; j < 10; ++j)
            wr[ff][j] = w[(f * 10 + j) * 1024 + o];
        br[ff] = bias[f * 1024 + o];
    }

    __syncthreads();

    // ---- Pure LDS + FMA + store loop: no global loads ----
    #pragma unroll 2
    for (int row = 0; row < BTILE; ++row) {
        const float* __restrict__ xr = &xs[row * (NSLOT * 64)];
        const float x0 = xr[lane];
        const float g0 = xr[lane ^ 1];
        const float g1 = xr[lane ^ 2];
        const float g2 = xr[lane ^ 4];
        const float g3 = xr[lane ^ 8];
        const float g4 = xr[lane ^ 16];
        const float g5 = xr[lane ^ 32];
        const float g6 = xr[64  + lane];   // o ^ 64
        const float g7 = xr[128 + lane];   // o ^ 128
        const float g8 = xr[192 + lane];   // o ^ 256
        const float g9 = xr[256 + lane];   // o ^ 512

        float* __restrict__ ob = out + (size_t)(b0 + row) * 16384 + chunk * 64 + lane;
        #pragma unroll
        for (int ff = 0; ff < 8; ++ff) {
            float acc = br[ff] + x0;          // bias + tiled-x term
            acc = fmaf(g0, wr[ff][0], acc);
            acc = fmaf(g1, wr[ff][1], acc);
            acc = fmaf(g2, wr[ff][2], acc);
            acc = fmaf(g3, wr[ff][3], acc);
            acc = fmaf(g4, wr[ff][4], acc);
            acc = fmaf(g5, wr[ff][5], acc);
            acc = fmaf(g6, wr[ff][6], acc);
            acc = fmaf(g7, wr[ff][7], acc);
            acc = fmaf(g8, wr[ff][8], acc);
            acc = fmaf(g9, wr[ff][9], acc);
            ob[(f0 + ff) * 1024] = acc;       // coalesced 256 B store
        }
    }
}

extern "C" void kernel_launch(void* const* d_in, const int* in_sizes, int n_in,
                              void* d_out, int out_size, void* d_ws, size_t ws_size,
                              hipStream_t stream) {
    const float* x    = (const float*)d_in[0];
    const float* w    = (const float*)d_in[1];
    const float* bias = (const float*)d_in[2];
    // d_in[3] = fm (int32) -- analytic, unused.
    float* out = (float*)d_out;

    dim3 grid(16 * (2048 / BTILE));   // 2048 blocks, 8/CU (LDS 20 KB x 8 = 160 KB)
    dim3 block(128);                  // 2 waves: f 0-7 and f 8-15
    hypercube_kernel<<<grid, block, 0, stream>>>(x, w, bias, out);
}